// Round 2
// baseline (3116.550 us; speedup 1.0000x reference)
//
#include <hip/hip_runtime.h>

// LSTMConditioned: conv-encoder + attention-LSTM (T=64) + MDN head.
// N=128, T=64, HID=512, COMB=1024, ATT=128, K=20, D=2, FMAP=64, L=196, ODIM=121.

#define TN 128
#define TT 64
#define THID 512
#define TATT 128
#define TFM 64
#define TL 196

typedef __attribute__((ext_vector_type(4))) float f32x4;
typedef __attribute__((ext_vector_type(8))) short bf16x8;

__device__ __forceinline__ float fsigm(float x){ return __builtin_amdgcn_rcpf(1.0f + __expf(-x)); }
__device__ __forceinline__ float ftanh(float x){ return 1.0f - 2.0f*__builtin_amdgcn_rcpf(1.0f + __expf(2.0f*x)); }
__device__ __forceinline__ unsigned short f2bf(float f){
  unsigned int u = __float_as_uint(f);
  u += 0x7fffu + ((u >> 16) & 1u);
  return (unsigned short)(u >> 16);
}

// ---------------- conv stack ----------------
__global__ __launch_bounds__(256) void k_conv1(const float* __restrict__ xc, const float* __restrict__ w,
                                               const float* __restrict__ b, float* __restrict__ c1){
  int idx = blockIdx.x*256 + threadIdx.x;
  if (idx >= TN*16*784) return;
  int p = idx % 784, oc = (idx/784) & 15, n = idx/(784*16);
  int py = p/28, px = p%28;
  const float* src = xc + n*784;
  float acc = b[oc];
  #pragma unroll
  for (int ky=0;ky<3;ky++){
    int iy = py+ky-1; if (iy<0||iy>=28) continue;
    #pragma unroll
    for (int kx=0;kx<3;kx++){
      int ix = px+kx-1; if (ix<0||ix>=28) continue;
      acc += (src[iy*28+ix]-0.0243f)*(1.0f/0.1383f) * w[oc*9+ky*3+kx];
    }
  }
  c1[idx] = fmaxf(acc, 0.0f);
}

__global__ __launch_bounds__(256) void k_conv2(const float* __restrict__ c1, const float* __restrict__ w,
                                               const float* __restrict__ b, float* __restrict__ c2){
  int idx = blockIdx.x*256 + threadIdx.x;
  if (idx >= TN*32*784) return;
  int p = idx % 784, oc = (idx/784) & 31, n = idx/(784*32);
  int py = p/28, px = p%28;
  const float* src = c1 + n*16*784;
  const float* wr = w + oc*144;
  float acc = b[oc];
  for (int ic=0; ic<16; ic++){
    #pragma unroll
    for (int ky=0;ky<3;ky++){
      int iy=py+ky-1; if(iy<0||iy>=28) continue;
      #pragma unroll
      for (int kx=0;kx<3;kx++){
        int ix=px+kx-1; if(ix<0||ix>=28) continue;
        acc += src[ic*784 + iy*28+ix]*wr[ic*9 + ky*3+kx];
      }
    }
  }
  c2[idx] = fmaxf(acc, 0.0f);
}

__global__ __launch_bounds__(256) void k_conv3(const float* __restrict__ c2, const float* __restrict__ w,
                                               const float* __restrict__ b, float* __restrict__ af,
                                               unsigned short* __restrict__ abf){
  int idx = blockIdx.x*256 + threadIdx.x;
  if (idx >= TN*64*196) return;
  int p = idx % 196, oc = (idx/196) & 63, n = idx/(196*64);
  int py = p/14, px = p%14;
  const float* src = c2 + n*32*784;
  const float* wr = w + oc*288;
  float acc = b[oc];
  for (int ic=0; ic<32; ic++){
    #pragma unroll
    for (int ky=0;ky<3;ky++){
      int iy=2*py+ky-1; if(iy<0||iy>=28) continue;
      #pragma unroll
      for (int kx=0;kx<3;kx++){
        int ix=2*px+kx-1; if(ix<0||ix>=28) continue;
        acc += src[ic*784 + iy*28+ix]*wr[ic*9 + ky*3+kx];
      }
    }
  }
  float v = ftanh(acc);
  af[(n*196+p)*64 + oc] = v;           // a[n][l][f], l = py*14+px
  abf[(n*196+p)*64 + oc] = f2bf(v);
}

__global__ __launch_bounds__(64) void k_amean(const float* __restrict__ af, float* __restrict__ amean){
  int n = blockIdx.x, f = threadIdx.x;
  float s = 0;
  for (int l=0;l<196;l++) s += af[(n*196+l)*64 + f];
  amean[n*64+f] = s * (1.0f/196.0f);
}

// ---------------- embeddings / init ----------------
__global__ __launch_bounds__(256) void k_embed(const float* __restrict__ x, const float* __restrict__ start,
    const float* __restrict__ xw, const float* __restrict__ xb,
    const float* __restrict__ sw, const float* __restrict__ sb,
    float* __restrict__ xe, float* __restrict__ se){
  int idx = blockIdx.x*256 + threadIdx.x;
  if (idx < TN*TT*16){
    int j = idx & 15, t = (idx>>4) & 63, n = idx>>10;
    float acc = xb[j];
    if (t > 0){
      const float* xp = x + (n*TT + t-1)*2;
      acc += xp[0]*xw[j*2] + xp[1]*xw[j*2+1];
    }
    xe[idx] = ftanh(acc);
  } else if (idx < TN*TT*16 + TN*16){
    int k2 = idx - TN*TT*16;
    int j = k2 & 15, n = k2 >> 4;
    float acc = sb[j] + start[n*2]*sw[j*2] + start[n*2+1]*sw[j*2+1];
    se[k2] = ftanh(acc);
  }
}

__global__ __launch_bounds__(256) void k_init(const float* __restrict__ amean, const float* __restrict__ se,
    const float* __restrict__ w, const float* __restrict__ b,
    float* __restrict__ hbuf, float* __restrict__ cbuf){
  int idx = blockIdx.x*256 + threadIdx.x;
  if (idx >= TN*1024) return;
  int o = idx & 1023, n = idx >> 10;
  const float* wr = w + o*80;
  float acc = b[o];
  for (int k2=0;k2<64;k2++) acc += amean[n*64+k2]*wr[k2];
  for (int k2=0;k2<16;k2++) acc += se[n*16+k2]*wr[64+k2];
  float v = ftanh(acc);
  if (o & 1) cbuf[n*512 + (o>>1)] = v;
  else       hbuf[n*512 + (o>>1)] = v;
}

// ---------------- weight prep (bf16 conversions, transposes, bias folds) ----------------
__global__ __launch_bounds__(256) void k_prep(
    const float* __restrict__ Whh, const float* __restrict__ Wih,
    const float* __restrict__ bih, const float* __restrict__ bhh,
    const float* __restrict__ comb_w, const float* __restrict__ out_w, const float* __restrict__ out_b,
    const float* __restrict__ Uw, const float* __restrict__ beta_w, const float* __restrict__ Ww,
    unsigned short* __restrict__ whh_bf, unsigned short* __restrict__ wih_bf, float* __restrict__ gbias,
    unsigned short* __restrict__ cwbf, unsigned short* __restrict__ owbf, float* __restrict__ obias,
    float* __restrict__ uwT, float* __restrict__ bwT, unsigned short* __restrict__ wwbf){
  int idx = blockIdx.x*256 + threadIdx.x;
  if (idx < 1048576){ whh_bf[idx] = f2bf(Whh[idx]); return; }
  idx -= 1048576;
  if (idx < 196608){ int o = idx/96, k2 = idx%96; wih_bf[idx] = (k2<80) ? f2bf(Wih[o*80+k2]) : (unsigned short)0; return; }
  idx -= 196608;
  if (idx < 2048){ gbias[idx] = bih[idx]+bhh[idx]; return; }
  idx -= 2048;
  if (idx < 622592){ cwbf[idx] = f2bf(comb_w[idx]); return; }
  idx -= 622592;
  if (idx < 131072){ int o = idx>>10, k2 = idx & 1023; owbf[idx] = (o<121)? f2bf(out_w[o*1024+k2]) : (unsigned short)0; return; }
  idx -= 131072;
  if (idx < 128){ obias[idx] = (idx<121)? out_b[idx] : 0.0f; return; }
  idx -= 128;
  if (idx < 65536){ int k2 = idx >> 7, att = idx & 127; uwT[idx] = Uw[att*512 + k2]; return; }
  idx -= 65536;
  if (idx < 32768){ int k2 = idx >> 6, f = idx & 63; bwT[idx] = beta_w[f*512 + k2]; return; }
  idx -= 32768;
  if (idx < 8192){ wwbf[idx] = f2bf(Ww[idx]); return; }
}

// ---------------- W_a = a @ Ww.T + Wb (MFMA), stored transposed [n][att][l] ----------------
__global__ __launch_bounds__(256) void k_wa(const unsigned short* __restrict__ abf,
    const unsigned short* __restrict__ wwbf, const float* __restrict__ Wb,
    float* __restrict__ waT){
  int mbase = blockIdx.x*128;
  int tid = threadIdx.x, w = tid>>6, l = tid&63;
  int lr = l & 15, lk = (l>>4)*8;
  __shared__ unsigned short at[128*40];
  f32x4 acc[8][2];
  #pragma unroll
  for (int m=0;m<8;m++){ acc[m][0] = (f32x4){0,0,0,0}; acc[m][1] = (f32x4){0,0,0,0}; }
  for (int kt=0; kt<2; ++kt){
    int row = tid>>1, half = (tid&1)*16;
    const unsigned short* sp = abf + (mbase+row)*64 + kt*32 + half;
    *(float4*)&at[row*40 + half]     = *(const float4*)sp;       // shorts [half, half+8)
    *(float4*)&at[row*40 + half + 8] = *(const float4*)(sp + 8); // shorts [half+8, half+16)
    __syncthreads();
    bf16x8 b0 = *(const bf16x8*)(wwbf + ((2*w+0)*16 + lr)*64 + kt*32 + lk);
    bf16x8 b1 = *(const bf16x8*)(wwbf + ((2*w+1)*16 + lr)*64 + kt*32 + lk);
    #pragma unroll
    for (int m=0;m<8;m++){
      bf16x8 afrag = *(const bf16x8*)&at[(m*16+lr)*40 + lk];
      acc[m][0] = __builtin_amdgcn_mfma_f32_16x16x32_bf16(afrag, b0, acc[m][0], 0,0,0);
      acc[m][1] = __builtin_amdgcn_mfma_f32_16x16x32_bf16(afrag, b1, acc[m][1], 0,0,0);
    }
    __syncthreads();
  }
  #pragma unroll
  for (int m=0;m<8;m++){
    #pragma unroll
    for (int j=0;j<2;j++){
      int att = (2*w+j)*16 + lr;
      float wb = Wb[att];
      #pragma unroll
      for (int i=0;i<4;i++){
        int arow = mbase + m*16 + (l>>4)*4 + i;
        int n = arow/196, l2 = arow - n*196;
        waT[(n*128 + att)*196 + l2] = acc[m][j][i] + wb;
      }
    }
  }
}

// ---------------- recurrent step A: cell update + attention (one block per sample) ----------------
__global__ __launch_bounds__(256) void k_stepA(int t,
    const float* __restrict__ gbuf, float* __restrict__ cbuf, const float* __restrict__ hbuf,
    const float* __restrict__ uwT, const float* __restrict__ Ub,
    const float* __restrict__ bwT, const float* __restrict__ beta_b,
    const float* __restrict__ vw, const float* __restrict__ vb,
    const float* __restrict__ waT, const float* __restrict__ af,
    const float* __restrict__ xe,
    unsigned short* __restrict__ hbf, unsigned short* __restrict__ ubf,
    unsigned short* __restrict__ cbf)
{
  int n = blockIdx.x, tid = threadIdx.x;
  __shared__ float hs[512];
  __shared__ float Uh[128];
  __shared__ float bsig[64];
  __shared__ float ew[196];
  __shared__ float red[256];
  __shared__ float zs[64];
  if (t > 0){
    const float* g = gbuf + n*2048;
    unsigned short* crow = cbf + (size_t)(n*TT + (t-1))*608;
    for (int j=tid; j<512; j+=256){
      float cc = cbuf[n*512+j];
      float cs = fsigm(g[512+j])*cc + fsigm(g[j])*ftanh(g[1024+j]);
      float h = fsigm(g[1536+j])*ftanh(cs);
      cbuf[n*512+j] = cs;
      hs[j] = h;
      unsigned short hb = f2bf(h);
      hbf[n*512+j] = hb;
      crow[j] = hb;                      // comb-input h slice for y_{t-1}
    }
  } else {
    for (int j=tid; j<512; j+=256){
      float h = hbuf[n*512+j];
      hs[j] = h;
      hbf[n*512+j] = f2bf(h);
    }
  }
  __syncthreads();
  if (t >= TT) return;
  // phase 1: Uh (lanes 0..127), beta-sigmoid (lanes 128..191)
  if (tid < 128){
    float acc = Ub[tid];
    for (int k2=0;k2<512;k2++) acc += hs[k2]*uwT[k2*128 + tid];
    Uh[tid] = acc;
  } else if (tid < 192){
    int f = tid-128;
    float acc = beta_b[f];
    for (int k2=0;k2<512;k2++) acc += hs[k2]*bwT[k2*64 + f];
    bsig[f] = fsigm(acc);
  }
  __syncthreads();
  // phase 2: e[l] = vb + sum_att vw[att]*tanh(W_a + Uh)
  if (tid < 196){
    const float* wr = waT + n*128*196 + tid;
    float acc = vb[0];
    for (int k2=0;k2<128;k2++) acc += vw[k2]*ftanh(wr[k2*196] + Uh[k2]);
    ew[tid] = acc;
  }
  __syncthreads();
  // softmax over 196
  float v = (tid<196) ? ew[tid] : -1e30f;
  red[tid] = v; __syncthreads();
  for (int s=128; s>0; s>>=1){ if (tid<s) red[tid] = fmaxf(red[tid], red[tid+s]); __syncthreads(); }
  float mx = red[0]; __syncthreads();
  float ex = (tid<196) ? __expf(v - mx) : 0.0f;
  if (tid<196) ew[tid] = ex;
  red[tid] = ex; __syncthreads();
  for (int s=128; s>0; s>>=1){ if (tid<s) red[tid] += red[tid+s]; __syncthreads(); }
  float inv = __builtin_amdgcn_rcpf(red[0]);
  __syncthreads();
  // phase 3: z[f] = bsig[f] * sum_l alpha[l]*a[n][l][f]
  if (tid < 64){
    float acc = 0;
    const float* an = af + n*196*64 + tid;
    for (int l2=0;l2<196;l2++) acc += ew[l2]*an[l2*64];
    zs[tid] = bsig[tid]*acc*inv;
  }
  __syncthreads();
  // write gates-input u = [xe_t(16), z(64), pad(16)] and comb-input z slice
  if (tid < 96){
    unsigned short val;
    if (tid < 16) val = f2bf(xe[(n*TT + t)*16 + tid]);
    else if (tid < 80) val = f2bf(zs[tid-16]);
    else val = 0;
    ubf[n*96 + tid] = val;
    if (tid >= 16 && tid < 80) cbf[(size_t)(n*TT + t)*608 + 512 + (tid-16)] = val;
  }
}

// ---------------- recurrent step B: gates = [u,h] @ [Wih,Whh].T + bias (MFMA) ----------------
__global__ __launch_bounds__(256) void k_stepB(const unsigned short* __restrict__ hbf,
    const unsigned short* __restrict__ ubf,
    const unsigned short* __restrict__ whh_bf, const unsigned short* __restrict__ wih_bf,
    const float* __restrict__ gbias, float* __restrict__ gbuf)
{
  int obase = blockIdx.x*64;
  int tid = threadIdx.x, w = tid>>6, l = tid&63;
  int lr = l&15, lk = (l>>4)*8;
  __shared__ unsigned short at[128*40];
  f32x4 acc[8];
  #pragma unroll
  for (int i=0;i<8;i++) acc[i] = (f32x4){0,0,0,0};
  for (int kt=0; kt<19; ++kt){
    int row = tid>>1, half = (tid&1)*16;
    const unsigned short* sp = (kt<16) ? (hbf + row*512 + kt*32 + half)
                                       : (ubf + row*96 + (kt-16)*32 + half);
    *(float4*)&at[row*40 + half]     = *(const float4*)sp;
    *(float4*)&at[row*40 + half + 8] = *(const float4*)(sp + 8);
    __syncthreads();
    bf16x8 bfrag = (kt<16)
      ? *(const bf16x8*)(whh_bf + (obase + w*16 + lr)*512 + kt*32 + lk)
      : *(const bf16x8*)(wih_bf + (obase + w*16 + lr)*96 + (kt-16)*32 + lk);
    #pragma unroll
    for (int nt=0; nt<8; ++nt){
      bf16x8 afrag = *(const bf16x8*)&at[(nt*16 + lr)*40 + lk];
      acc[nt] = __builtin_amdgcn_mfma_f32_16x16x32_bf16(afrag, bfrag, acc[nt], 0,0,0);
    }
    __syncthreads();
  }
  int o = obase + w*16 + lr;
  float gb = gbias[o];
  #pragma unroll
  for (int nt=0; nt<8; ++nt){
    #pragma unroll
    for (int i=0;i<4;i++){
      int n = nt*16 + (l>>4)*4 + i;
      gbuf[n*2048 + o] = acc[nt][i] + gb;
    }
  }
}

// ---------------- comb-input xe/se slices ----------------
__global__ __launch_bounds__(256) void k_cbf_xs(const float* __restrict__ xe, const float* __restrict__ se,
                                                unsigned short* __restrict__ cbf){
  int idx = blockIdx.x*256 + threadIdx.x;
  if (idx >= TN*TT*32) return;
  int j = idx & 31, r = idx >> 5;
  int n = r >> 6;
  if (j < 16) cbf[(size_t)r*608 + 576 + j] = f2bf(xe[r*16 + j]);
  else        cbf[(size_t)r*608 + 592 + (j-16)] = f2bf(se[n*16 + (j-16)]);
}

// ---------------- comb GEMM: y = tanh(cin @ comb_w.T + comb_b), bf16 out ----------------
__global__ __launch_bounds__(256) void k_comb(const unsigned short* __restrict__ cbf,
    const unsigned short* __restrict__ cwbf, const float* __restrict__ comb_b,
    unsigned short* __restrict__ ybf){
  int mbase = blockIdx.x*128, obase = blockIdx.y*128;
  int tid = threadIdx.x, w = tid>>6, l = tid&63;
  int lr = l&15, lk = (l>>4)*8;
  __shared__ unsigned short at[128*40];
  f32x4 acc[8][2];
  #pragma unroll
  for (int m=0;m<8;m++){ acc[m][0] = (f32x4){0,0,0,0}; acc[m][1] = (f32x4){0,0,0,0}; }
  for (int kt=0; kt<19; ++kt){
    int row = tid>>1, half = (tid&1)*16;
    const unsigned short* sp = cbf + (size_t)(mbase+row)*608 + kt*32 + half;
    *(float4*)&at[row*40 + half]     = *(const float4*)sp;
    *(float4*)&at[row*40 + half + 8] = *(const float4*)(sp + 8);
    __syncthreads();
    bf16x8 b0 = *(const bf16x8*)(cwbf + (size_t)(obase + (2*w+0)*16 + lr)*608 + kt*32 + lk);
    bf16x8 b1 = *(const bf16x8*)(cwbf + (size_t)(obase + (2*w+1)*16 + lr)*608 + kt*32 + lk);
    #pragma unroll
    for (int m=0;m<8;m++){
      bf16x8 afrag = *(const bf16x8*)&at[(m*16+lr)*40 + lk];
      acc[m][0] = __builtin_amdgcn_mfma_f32_16x16x32_bf16(afrag, b0, acc[m][0], 0,0,0);
      acc[m][1] = __builtin_amdgcn_mfma_f32_16x16x32_bf16(afrag, b1, acc[m][1], 0,0,0);
    }
    __syncthreads();
  }
  #pragma unroll
  for (int m=0;m<8;m++){
    #pragma unroll
    for (int j=0;j<2;j++){
      int o = obase + (2*w+j)*16 + lr;
      float cb = comb_b[o];
      #pragma unroll
      for (int i=0;i<4;i++){
        int r = mbase + m*16 + (l>>4)*4 + i;
        ybf[(size_t)r*1024 + o] = f2bf(ftanh(acc[m][j][i] + cb));
      }
    }
  }
}

// ---------------- out GEMM: obuf = y @ out_w.T + out_b (N padded 121->128) ----------------
__global__ __launch_bounds__(256) void k_out(const unsigned short* __restrict__ ybf,
    const unsigned short* __restrict__ owbf, const float* __restrict__ obias,
    float* __restrict__ obuf){
  int mbase = blockIdx.x*128;
  int tid = threadIdx.x, w = tid>>6, l = tid&63;
  int lr = l&15, lk = (l>>4)*8;
  __shared__ unsigned short at[128*40];
  f32x4 acc[8][2];
  #pragma unroll
  for (int m=0;m<8;m++){ acc[m][0] = (f32x4){0,0,0,0}; acc[m][1] = (f32x4){0,0,0,0}; }
  for (int kt=0; kt<32; ++kt){
    int row = tid>>1, half = (tid&1)*16;
    const unsigned short* sp = ybf + (size_t)(mbase+row)*1024 + kt*32 + half;
    *(float4*)&at[row*40 + half]     = *(const float4*)sp;
    *(float4*)&at[row*40 + half + 8] = *(const float4*)(sp + 8);
    __syncthreads();
    bf16x8 b0 = *(const bf16x8*)(owbf + ((2*w+0)*16 + lr)*1024 + kt*32 + lk);
    bf16x8 b1 = *(const bf16x8*)(owbf + ((2*w+1)*16 + lr)*1024 + kt*32 + lk);
    #pragma unroll
    for (int m=0;m<8;m++){
      bf16x8 afrag = *(const bf16x8*)&at[(m*16+lr)*40 + lk];
      acc[m][0] = __builtin_amdgcn_mfma_f32_16x16x32_bf16(afrag, b0, acc[m][0], 0,0,0);
      acc[m][1] = __builtin_amdgcn_mfma_f32_16x16x32_bf16(afrag, b1, acc[m][1], 0,0,0);
    }
    __syncthreads();
  }
  #pragma unroll
  for (int m=0;m<8;m++){
    #pragma unroll
    for (int j=0;j<2;j++){
      int o = (2*w+j)*16 + lr;
      float ob = obias[o];
      #pragma unroll
      for (int i=0;i<4;i++){
        int r = mbase + m*16 + (l>>4)*4 + i;
        obuf[(size_t)r*128 + o] = acc[m][j][i] + ob;
      }
    }
  }
}

// ---------------- postprocess: split + softmax/exp/tanh ----------------
__global__ __launch_bounds__(256) void k_post(const float* __restrict__ obuf, float* __restrict__ out){
  int r = blockIdx.x*256 + threadIdx.x;
  if (r >= TN*TT) return;
  const float* row = obuf + (size_t)r*128;
  float mx = -1e30f;
  #pragma unroll
  for (int k2=0;k2<20;k2++) mx = fmaxf(mx, row[k2]);
  float e[20]; float s = 0;
  #pragma unroll
  for (int k2=0;k2<20;k2++){ e[k2] = __expf(row[k2]-mx); s += e[k2]; }
  float inv = __builtin_amdgcn_rcpf(s);
  float* mixo  = out;
  float* meano = out + 163840;
  float* scaleo= out + 491520;
  float* corro = out + 819200;
  float* vlogo = out + 983040;
  #pragma unroll
  for (int k2=0;k2<20;k2++) mixo[r*20+k2] = e[k2]*inv;
  #pragma unroll
  for (int j=0;j<40;j++) meano[r*40+j] = row[20+j];
  #pragma unroll
  for (int j=0;j<40;j++) scaleo[r*40+j] = __expf(row[60+j]);
  #pragma unroll
  for (int k2=0;k2<20;k2++) corro[r*20+k2] = ftanh(row[100+k2]);
  vlogo[r] = row[120];
}

extern "C" void kernel_launch(void* const* d_in, const int* in_sizes, int n_in,
                              void* d_out, int out_size, void* d_ws, size_t ws_size,
                              hipStream_t stream){
  const float* x       = (const float*)d_in[0];
  const float* x_canv  = (const float*)d_in[1];
  const float* start_  = (const float*)d_in[2];
  const float* conv1_w = (const float*)d_in[3];
  const float* conv1_b = (const float*)d_in[4];
  const float* conv2_w = (const float*)d_in[5];
  const float* conv2_b = (const float*)d_in[6];
  const float* conv3_w = (const float*)d_in[7];
  const float* conv3_b = (const float*)d_in[8];
  const float* init_w  = (const float*)d_in[9];
  const float* init_b  = (const float*)d_in[10];
  const float* Uw      = (const float*)d_in[11];
  const float* Ub      = (const float*)d_in[12];
  const float* Ww      = (const float*)d_in[13];
  const float* Wb      = (const float*)d_in[14];
  const float* vw      = (const float*)d_in[15];
  const float* vb      = (const float*)d_in[16];
  const float* beta_w  = (const float*)d_in[17];
  const float* beta_b  = (const float*)d_in[18];
  const float* xemb_w  = (const float*)d_in[19];
  const float* xemb_b  = (const float*)d_in[20];
  const float* semb_w  = (const float*)d_in[21];
  const float* semb_b  = (const float*)d_in[22];
  const float* Wih     = (const float*)d_in[23];
  const float* Whh     = (const float*)d_in[24];
  const float* bih     = (const float*)d_in[25];
  const float* bhh     = (const float*)d_in[26];
  const float* comb_w  = (const float*)d_in[27];
  const float* comb_b  = (const float*)d_in[28];
  const float* out_w   = (const float*)d_in[29];
  const float* out_b   = (const float*)d_in[30];
  (void)in_sizes; (void)n_in; (void)out_size; (void)ws_size;

  char* wsb = (char*)d_ws;
  size_t off = 0;
  auto alloc = [&](size_t bytes)->char*{
    char* p = wsb + off;
    off = (off + bytes + 255) & ~(size_t)255;
    return p;
  };
  float*          c1     = (float*)alloc((size_t)TN*16*784*4);
  float*          c2     = (float*)alloc((size_t)TN*32*784*4);
  float*          af     = (float*)alloc((size_t)TN*196*64*4);
  unsigned short* abf    = (unsigned short*)alloc((size_t)TN*196*64*2);
  float*          amean  = (float*)alloc((size_t)TN*64*4);
  float*          xe     = (float*)alloc((size_t)TN*TT*16*4);
  float*          se     = (float*)alloc((size_t)TN*16*4);
  float*          waT    = (float*)alloc((size_t)TN*128*196*4);
  float*          hbuf   = (float*)alloc((size_t)TN*512*4);
  float*          cbuf   = (float*)alloc((size_t)TN*512*4);
  float*          gbuf   = (float*)alloc((size_t)TN*2048*4);
  unsigned short* hbf    = (unsigned short*)alloc((size_t)TN*512*2);
  unsigned short* ubf    = (unsigned short*)alloc((size_t)TN*96*2);
  unsigned short* cbf    = (unsigned short*)alloc((size_t)TN*TT*608*2);
  unsigned short* ybf    = (unsigned short*)alloc((size_t)TN*TT*1024*2);
  float*          obuf   = (float*)alloc((size_t)TN*TT*128*4);
  unsigned short* whh_bf = (unsigned short*)alloc((size_t)2048*512*2);
  unsigned short* wih_bf = (unsigned short*)alloc((size_t)2048*96*2);
  float*          gbias  = (float*)alloc((size_t)2048*4);
  unsigned short* cwbf   = (unsigned short*)alloc((size_t)1024*608*2);
  unsigned short* owbf   = (unsigned short*)alloc((size_t)128*1024*2);
  float*          obias  = (float*)alloc((size_t)128*4);
  float*          uwT    = (float*)alloc((size_t)512*128*4);
  float*          bwT    = (float*)alloc((size_t)512*64*4);
  unsigned short* wwbf   = (unsigned short*)alloc((size_t)128*64*2);

  hipLaunchKernelGGL(k_conv1, dim3(6272), dim3(256), 0, stream, x_canv, conv1_w, conv1_b, c1);
  hipLaunchKernelGGL(k_conv2, dim3(12544), dim3(256), 0, stream, c1, conv2_w, conv2_b, c2);
  hipLaunchKernelGGL(k_conv3, dim3(6272), dim3(256), 0, stream, c2, conv3_w, conv3_b, af, abf);
  hipLaunchKernelGGL(k_amean, dim3(128), dim3(64), 0, stream, af, amean);
  hipLaunchKernelGGL(k_embed, dim3(520), dim3(256), 0, stream, x, start_, xemb_w, xemb_b, semb_w, semb_b, xe, se);
  hipLaunchKernelGGL(k_init, dim3(512), dim3(256), 0, stream, amean, se, init_w, init_b, hbuf, cbuf);
  hipLaunchKernelGGL(k_prep, dim3(8233), dim3(256), 0, stream,
                     Whh, Wih, bih, bhh, comb_w, out_w, out_b, Uw, beta_w, Ww,
                     whh_bf, wih_bf, gbias, cwbf, owbf, obias, uwT, bwT, wwbf);
  hipLaunchKernelGGL(k_wa, dim3(196), dim3(256), 0, stream, abf, wwbf, Wb, waT);
  hipLaunchKernelGGL(k_cbf_xs, dim3(1024), dim3(256), 0, stream, xe, se, cbf);

  for (int t = 0; t <= TT; ++t){
    hipLaunchKernelGGL(k_stepA, dim3(128), dim3(256), 0, stream, t,
                       gbuf, cbuf, hbuf, uwT, Ub, bwT, beta_b, vw, vb, waT, af, xe,
                       hbf, ubf, cbf);
    if (t < TT){
      hipLaunchKernelGGL(k_stepB, dim3(32), dim3(256), 0, stream,
                         hbf, ubf, whh_bf, wih_bf, gbias, gbuf);
    }
  }

  hipLaunchKernelGGL(k_comb, dim3(64, 8), dim3(256), 0, stream, cbf, cwbf, comb_b, ybf);
  hipLaunchKernelGGL(k_out, dim3(64), dim3(256), 0, stream, ybf, owbf, obias, obuf);
  hipLaunchKernelGGL(k_post, dim3(32), dim3(256), 0, stream, obuf, (float*)d_out);
}

// Round 3
// 2666.900 us; speedup vs baseline: 1.1686x; 1.1686x over previous
//
#include <hip/hip_runtime.h>

// LSTMConditioned: conv-encoder + attention-LSTM (T=64) + MDN head.
// N=128, T=64, HID=512, COMB=1024, ATT=128, K=20, D=2, FMAP=64, L=196, ODIM=121.

#define TN 128
#define TT 64

typedef __attribute__((ext_vector_type(4))) float f32x4;
typedef __attribute__((ext_vector_type(8))) short bf16x8;

__device__ __forceinline__ float fsigm(float x){ return __builtin_amdgcn_rcpf(1.0f + __expf(-x)); }
__device__ __forceinline__ float ftanh(float x){ return 1.0f - 2.0f*__builtin_amdgcn_rcpf(1.0f + __expf(2.0f*x)); }
__device__ __forceinline__ unsigned short f2bf(float f){
  unsigned int u = __float_as_uint(f);
  u += 0x7fffu + ((u >> 16) & 1u);
  return (unsigned short)(u >> 16);
}

// ---------------- conv1 (direct, small) ----------------
__global__ __launch_bounds__(256) void k_conv1(const float* __restrict__ xc, const float* __restrict__ w,
                                               const float* __restrict__ b, float* __restrict__ c1){
  int idx = blockIdx.x*256 + threadIdx.x;
  if (idx >= TN*16*784) return;
  int p = idx % 784, oc = (idx/784) & 15, n = idx/(784*16);
  int py = p/28, px = p%28;
  const float* src = xc + n*784;
  float acc = b[oc];
  #pragma unroll
  for (int ky=0;ky<3;ky++){
    int iy = py+ky-1; if (iy<0||iy>=28) continue;
    #pragma unroll
    for (int kx=0;kx<3;kx++){
      int ix = px+kx-1; if (ix<0||ix>=28) continue;
      acc += (src[iy*28+ix]-0.0243f)*(1.0f/0.1383f) * w[oc*9+ky*3+kx];
    }
  }
  c1[idx] = fmaxf(acc, 0.0f);
}

// ---------------- im2col for conv2: a2[r=n*784+p][k=ic*9+ky*3+kx], K pad 144->160, bf16 ----------------
__global__ __launch_bounds__(256) void k_im2col2(const float* __restrict__ c1, unsigned short* __restrict__ a2){
  int idx = blockIdx.x*256 + threadIdx.x;   // grid 62720*256 = 100352*160 exact
  int k = idx % 160, r = idx / 160;
  unsigned short v = 0;
  if (k < 144){
    int ic = k/9, rem = k - ic*9, ky = rem/3, kx = rem - ky*3;
    int p = r % 784, n = r / 784;
    int py = p/28, px = p%28;
    int iy = py+ky-1, ix = px+kx-1;
    if (iy>=0 && iy<28 && ix>=0 && ix<28) v = f2bf(c1[(n*16+ic)*784 + iy*28+ix]);
  }
  a2[idx] = v;
}

// ---------------- conv2 GEMM: c2bf[r][oc<32] = relu(a2 @ w2b.T + b), bf16 out ----------------
__global__ __launch_bounds__(256) void k_gconv2(const unsigned short* __restrict__ a2,
    const unsigned short* __restrict__ w2b, const float* __restrict__ b2,
    unsigned short* __restrict__ c2bf){
  int mbase = blockIdx.x*128;           // 784 blocks
  int tid = threadIdx.x, w = tid>>6, l = tid&63;
  int lr = l&15, lk = (l>>4)*8;
  __shared__ unsigned short at[128*168];
  {
    int row = tid>>1, off = (tid&1)*80;
    const unsigned short* sp = a2 + (size_t)(mbase+row)*160 + off;
    #pragma unroll
    for (int j=0;j<10;j++) *(float4*)&at[row*168 + off + j*8] = *(const float4*)(sp + j*8);
  }
  __syncthreads();
  f32x4 acc[2][2];
  #pragma unroll
  for (int mi=0;mi<2;mi++){ acc[mi][0]=(f32x4){0,0,0,0}; acc[mi][1]=(f32x4){0,0,0,0}; }
  for (int kt=0; kt<5; ++kt){
    bf16x8 b0 = *(const bf16x8*)(w2b + (0*16+lr)*160 + kt*32 + lk);
    bf16x8 b1 = *(const bf16x8*)(w2b + (1*16+lr)*160 + kt*32 + lk);
    #pragma unroll
    for (int mi=0;mi<2;mi++){
      bf16x8 afrag = *(const bf16x8*)&at[((2*w+mi)*16+lr)*168 + kt*32 + lk];
      acc[mi][0] = __builtin_amdgcn_mfma_f32_16x16x32_bf16(afrag, b0, acc[mi][0], 0,0,0);
      acc[mi][1] = __builtin_amdgcn_mfma_f32_16x16x32_bf16(afrag, b1, acc[mi][1], 0,0,0);
    }
  }
  #pragma unroll
  for (int mi=0;mi<2;mi++){
    #pragma unroll
    for (int j=0;j<2;j++){
      int oc = j*16 + lr;
      float bb = b2[oc];
      #pragma unroll
      for (int i=0;i<4;i++){
        int r = mbase + (2*w+mi)*16 + (l>>4)*4 + i;
        c2bf[(size_t)r*32 + oc] = f2bf(fmaxf(acc[mi][j][i] + bb, 0.0f));
      }
    }
  }
}

// ---------------- im2col for conv3 (stride 2): a3[r=n*196+q][k=ic*9+ky*3+kx], K pad 288->320 ----------------
__global__ __launch_bounds__(256) void k_im2col3(const unsigned short* __restrict__ c2bf, unsigned short* __restrict__ a3){
  int idx = blockIdx.x*256 + threadIdx.x;   // grid 31360*256 = 25088*320 exact
  int k = idx % 320, r = idx / 320;
  unsigned short v = 0;
  if (k < 288){
    int ic = k/9, rem = k - ic*9, ky = rem/3, kx = rem - ky*3;
    int p = r % 196, n = r / 196;
    int py = p/14, px = p%14;
    int iy = 2*py+ky-1, ix = 2*px+kx-1;
    if (iy>=0 && iy<28 && ix>=0 && ix<28) v = c2bf[(size_t)(n*784 + iy*28+ix)*32 + ic];
  }
  a3[idx] = v;
}

// ---------------- conv3 GEMM: af/abf[r][oc<64] = tanh(a3 @ w3b.T + b) ----------------
__global__ __launch_bounds__(256) void k_gconv3(const unsigned short* __restrict__ a3,
    const unsigned short* __restrict__ w3b, const float* __restrict__ b3,
    float* __restrict__ af, unsigned short* __restrict__ abf){
  int mbase = blockIdx.x*128;           // 196 blocks
  int tid = threadIdx.x, w = tid>>6, l = tid&63;
  int lr = l&15, lk = (l>>4)*8;
  __shared__ unsigned short at[128*168];
  f32x4 acc[2][4];
  #pragma unroll
  for (int mi=0;mi<2;mi++)
    #pragma unroll
    for (int j=0;j<4;j++) acc[mi][j]=(f32x4){0,0,0,0};
  for (int kt2=0; kt2<2; ++kt2){
    {
      int row = tid>>1, off = (tid&1)*80;
      const unsigned short* sp = a3 + (size_t)(mbase+row)*320 + kt2*160 + off;
      #pragma unroll
      for (int j=0;j<10;j++) *(float4*)&at[row*168 + off + j*8] = *(const float4*)(sp + j*8);
    }
    __syncthreads();
    for (int kt=0; kt<5; ++kt){
      #pragma unroll
      for (int mi=0;mi<2;mi++){
        bf16x8 afrag = *(const bf16x8*)&at[((2*w+mi)*16+lr)*168 + kt*32 + lk];
        #pragma unroll
        for (int j=0;j<4;j++){
          bf16x8 bf = *(const bf16x8*)(w3b + (size_t)(j*16+lr)*320 + kt2*160 + kt*32 + lk);
          acc[mi][j] = __builtin_amdgcn_mfma_f32_16x16x32_bf16(afrag, bf, acc[mi][j], 0,0,0);
        }
      }
    }
    __syncthreads();
  }
  #pragma unroll
  for (int mi=0;mi<2;mi++){
    #pragma unroll
    for (int j=0;j<4;j++){
      int oc = j*16 + lr;
      float bb = b3[oc];
      #pragma unroll
      for (int i=0;i<4;i++){
        int r = mbase + (2*w+mi)*16 + (l>>4)*4 + i;
        float v = ftanh(acc[mi][j][i] + bb);
        af[(size_t)r*64 + oc] = v;
        abf[(size_t)r*64 + oc] = f2bf(v);
      }
    }
  }
}

__global__ __launch_bounds__(64) void k_amean(const float* __restrict__ af, float* __restrict__ amean){
  int n = blockIdx.x, f = threadIdx.x;
  float s = 0;
  for (int l=0;l<196;l++) s += af[(n*196+l)*64 + f];
  amean[n*64+f] = s * (1.0f/196.0f);
}

// ---------------- embeddings / init ----------------
__global__ __launch_bounds__(256) void k_embed(const float* __restrict__ x, const float* __restrict__ start,
    const float* __restrict__ xw, const float* __restrict__ xb,
    const float* __restrict__ sw, const float* __restrict__ sb,
    float* __restrict__ xe, float* __restrict__ se){
  int idx = blockIdx.x*256 + threadIdx.x;
  if (idx < TN*TT*16){
    int j = idx & 15, t = (idx>>4) & 63, n = idx>>10;
    float acc = xb[j];
    if (t > 0){
      const float* xp = x + (n*TT + t-1)*2;
      acc += xp[0]*xw[j*2] + xp[1]*xw[j*2+1];
    }
    xe[idx] = ftanh(acc);
  } else if (idx < TN*TT*16 + TN*16){
    int k2 = idx - TN*TT*16;
    int j = k2 & 15, n = k2 >> 4;
    float acc = sb[j] + start[n*2]*sw[j*2] + start[n*2+1]*sw[j*2+1];
    se[k2] = ftanh(acc);
  }
}

__global__ __launch_bounds__(256) void k_init(const float* __restrict__ amean, const float* __restrict__ se,
    const float* __restrict__ w, const float* __restrict__ b,
    float* __restrict__ hbuf, float* __restrict__ cbuf){
  int idx = blockIdx.x*256 + threadIdx.x;
  if (idx >= TN*1024) return;
  int o = idx & 1023, n = idx >> 10;
  const float* wr = w + o*80;
  float acc = b[o];
  for (int k2=0;k2<64;k2++) acc += amean[n*64+k2]*wr[k2];
  for (int k2=0;k2<16;k2++) acc += se[n*16+k2]*wr[64+k2];
  float v = ftanh(acc);
  if (o & 1) cbuf[n*512 + (o>>1)] = v;
  else       hbuf[n*512 + (o>>1)] = v;
}

// ---------------- weight prep ----------------
__global__ __launch_bounds__(256) void k_prep(
    const float* __restrict__ Whh, const float* __restrict__ Wih,
    const float* __restrict__ bih, const float* __restrict__ bhh,
    const float* __restrict__ comb_w, const float* __restrict__ out_w, const float* __restrict__ out_b,
    const float* __restrict__ Uw, const float* __restrict__ beta_w, const float* __restrict__ Ww,
    const float* __restrict__ conv2_w, const float* __restrict__ conv3_w,
    unsigned short* __restrict__ whh_bf, unsigned short* __restrict__ wih_bf, float* __restrict__ gbias,
    unsigned short* __restrict__ cwbf, unsigned short* __restrict__ owbf, float* __restrict__ obias,
    float* __restrict__ uwT, float* __restrict__ bwT, unsigned short* __restrict__ wwbf,
    unsigned short* __restrict__ w2b, unsigned short* __restrict__ w3b){
  int idx = blockIdx.x*256 + threadIdx.x;
  if (idx < 1048576){ whh_bf[idx] = f2bf(Whh[idx]); return; }
  idx -= 1048576;
  if (idx < 196608){ int o = idx/96, k2 = idx%96; wih_bf[idx] = (k2<80) ? f2bf(Wih[o*80+k2]) : (unsigned short)0; return; }
  idx -= 196608;
  if (idx < 2048){ gbias[idx] = bih[idx]+bhh[idx]; return; }
  idx -= 2048;
  if (idx < 622592){ cwbf[idx] = f2bf(comb_w[idx]); return; }
  idx -= 622592;
  if (idx < 131072){ int o = idx>>10, k2 = idx & 1023; owbf[idx] = (o<121)? f2bf(out_w[o*1024+k2]) : (unsigned short)0; return; }
  idx -= 131072;
  if (idx < 128){ obias[idx] = (idx<121)? out_b[idx] : 0.0f; return; }
  idx -= 128;
  if (idx < 65536){ int k2 = idx >> 7, att = idx & 127; uwT[idx] = Uw[att*512 + k2]; return; }
  idx -= 65536;
  if (idx < 32768){ int k2 = idx >> 6, f = idx & 63; bwT[idx] = beta_w[f*512 + k2]; return; }
  idx -= 32768;
  if (idx < 8192){ wwbf[idx] = f2bf(Ww[idx]); return; }
  idx -= 8192;
  if (idx < 5120){ int o = idx/160, k2 = idx - o*160; w2b[idx] = (k2<144)? f2bf(conv2_w[o*144+k2]) : (unsigned short)0; return; }
  idx -= 5120;
  if (idx < 20480){ int o = idx/320, k2 = idx - o*320; w3b[idx] = (k2<288)? f2bf(conv3_w[o*288+k2]) : (unsigned short)0; return; }
}

// ---------------- W_a = a @ Ww.T + Wb (MFMA), stored transposed [n][att][l] ----------------
__global__ __launch_bounds__(256) void k_wa(const unsigned short* __restrict__ abf,
    const unsigned short* __restrict__ wwbf, const float* __restrict__ Wb,
    float* __restrict__ waT){
  int mbase = blockIdx.x*128;
  int tid = threadIdx.x, w = tid>>6, l = tid&63;
  int lr = l & 15, lk = (l>>4)*8;
  __shared__ unsigned short at[128*40];
  f32x4 acc[8][2];
  #pragma unroll
  for (int m=0;m<8;m++){ acc[m][0] = (f32x4){0,0,0,0}; acc[m][1] = (f32x4){0,0,0,0}; }
  for (int kt=0; kt<2; ++kt){
    int row = tid>>1, half = (tid&1)*16;
    const unsigned short* sp = abf + (mbase+row)*64 + kt*32 + half;
    *(float4*)&at[row*40 + half]     = *(const float4*)sp;
    *(float4*)&at[row*40 + half + 8] = *(const float4*)(sp + 8);
    __syncthreads();
    bf16x8 b0 = *(const bf16x8*)(wwbf + ((2*w+0)*16 + lr)*64 + kt*32 + lk);
    bf16x8 b1 = *(const bf16x8*)(wwbf + ((2*w+1)*16 + lr)*64 + kt*32 + lk);
    #pragma unroll
    for (int m=0;m<8;m++){
      bf16x8 afrag = *(const bf16x8*)&at[(m*16+lr)*40 + lk];
      acc[m][0] = __builtin_amdgcn_mfma_f32_16x16x32_bf16(afrag, b0, acc[m][0], 0,0,0);
      acc[m][1] = __builtin_amdgcn_mfma_f32_16x16x32_bf16(afrag, b1, acc[m][1], 0,0,0);
    }
    __syncthreads();
  }
  #pragma unroll
  for (int m=0;m<8;m++){
    #pragma unroll
    for (int j=0;j<2;j++){
      int att = (2*w+j)*16 + lr;
      float wb = Wb[att];
      #pragma unroll
      for (int i=0;i<4;i++){
        int arow = mbase + m*16 + (l>>4)*4 + i;
        int n = arow/196, l2 = arow - n*196;
        waT[(n*128 + att)*196 + l2] = acc[m][j][i] + wb;
      }
    }
  }
}

// ---------------- step A: attention (one block per sample) ----------------
__global__ __launch_bounds__(256) void k_stepA(int t,
    const float* __restrict__ hbuf,
    const float* __restrict__ uwT, const float* __restrict__ Ub,
    const float* __restrict__ bwT, const float* __restrict__ beta_b,
    const float* __restrict__ vw, const float* __restrict__ vb,
    const float* __restrict__ waT, const float* __restrict__ af,
    const float* __restrict__ xe,
    unsigned short* __restrict__ hbf0, unsigned short* __restrict__ ubf,
    unsigned short* __restrict__ cbf)
{
  int n = blockIdx.x, tid = threadIdx.x;
  __shared__ float hs[512];
  __shared__ float Uh[128];
  __shared__ float vws[128];
  __shared__ float bsig[64];
  __shared__ float ew[196];
  __shared__ float red[256];
  __shared__ float zs[64];
  __shared__ float up[2][128];
  __shared__ float qp[4][64];
  for (int j=tid; j<512; j+=256){
    float h = hbuf[n*512+j];
    hs[j] = h;
    if (t == 0) hbf0[n*512+j] = f2bf(h);
  }
  if (tid < 128) vws[tid] = vw[tid];
  __syncthreads();
  // phase 1a: Uh partial (128 att x 2 k-halves)
  {
    int att = tid & 127, kh = tid >> 7;
    const float* uw = uwT + (kh*256)*128 + att;
    const float* hh = hs + kh*256;
    float acc = 0.f;
    #pragma unroll 8
    for (int k2=0;k2<256;k2++) acc += hh[k2]*uw[k2*128];
    up[kh][att] = acc;
  }
  // phase 1b: beta partial (64 f x 4 k-quarters)
  {
    int f = tid & 63, q = tid >> 6;
    const float* bw = bwT + (q*128)*64 + f;
    const float* hh = hs + q*128;
    float acc = 0.f;
    #pragma unroll 8
    for (int k2=0;k2<128;k2++) acc += hh[k2]*bw[k2*64];
    qp[q][f] = acc;
  }
  __syncthreads();
  if (tid < 128) Uh[tid] = Ub[tid] + up[0][tid] + up[1][tid];
  else if (tid < 192){ int f = tid-128; bsig[f] = fsigm(beta_b[f] + qp[0][f]+qp[1][f]+qp[2][f]+qp[3][f]); }
  __syncthreads();
  // phase 2: e[l]
  if (tid < 196){
    const float* wr = waT + n*128*196 + tid;
    float acc = vb[0];
    #pragma unroll 4
    for (int k2=0;k2<128;k2++) acc += vws[k2]*ftanh(wr[k2*196] + Uh[k2]);
    ew[tid] = acc;
  }
  __syncthreads();
  // softmax over 196
  float v = (tid<196) ? ew[tid] : -1e30f;
  red[tid] = v; __syncthreads();
  for (int s=128; s>0; s>>=1){ if (tid<s) red[tid] = fmaxf(red[tid], red[tid+s]); __syncthreads(); }
  float mx = red[0]; __syncthreads();
  float ex = (tid<196) ? __expf(v - mx) : 0.0f;
  if (tid<196) ew[tid] = ex;
  red[tid] = ex; __syncthreads();
  for (int s=128; s>0; s>>=1){ if (tid<s) red[tid] += red[tid+s]; __syncthreads(); }
  float inv = __builtin_amdgcn_rcpf(red[0]);
  __syncthreads();
  // phase 3: z partial (64 f x 4 l-chunks of 49)
  {
    int f = tid & 63, q = tid >> 6;
    float acc = 0.f;
    const float* an = af + n*196*64 + f;
    int l0 = q*49;
    for (int l2=l0; l2<l0+49; l2++) acc += ew[l2]*an[l2*64];
    qp[q][f] = acc;
  }
  __syncthreads();
  if (tid < 64) zs[tid] = bsig[tid]*(qp[0][tid]+qp[1][tid]+qp[2][tid]+qp[3][tid])*inv;
  __syncthreads();
  // write gates-input u = [xe_t(16), z(64), pad(16)] and comb-input z slice
  if (tid < 96){
    unsigned short val;
    if (tid < 16) val = f2bf(xe[(n*TT + t)*16 + tid]);
    else if (tid < 80) val = f2bf(zs[tid-16]);
    else val = 0;
    ubf[n*96 + tid] = val;
    if (tid >= 16 && tid < 80) cbf[(size_t)(n*TT + t)*608 + 512 + (tid-16)] = val;
  }
}

// ---------------- step B: gates GEMM + fused cell update ----------------
// block b owns h-slice [b*16, b*16+16); wave w computes gate w for that slice.
__global__ __launch_bounds__(256) void k_stepB(int t,
    const unsigned short* __restrict__ hbf_in,
    const unsigned short* __restrict__ ubf,
    const unsigned short* __restrict__ whh_bf, const unsigned short* __restrict__ wih_bf,
    const float* __restrict__ gbias,
    float* __restrict__ cbuf, float* __restrict__ hbuf,
    unsigned short* __restrict__ hbf_out, unsigned short* __restrict__ cbf)
{
  int b = blockIdx.x;
  int tid = threadIdx.x, w = tid>>6, l = tid&63;
  int lr = l&15, lk = (l>>4)*8;
  __shared__ unsigned short at[128*40];
  __shared__ float gsh[4][128][16];
  f32x4 acc[8];
  #pragma unroll
  for (int i=0;i<8;i++) acc[i] = (f32x4){0,0,0,0};
  int ow = b*16 + w*512 + lr;   // weight/bias row for this wave's gate, col lr
  for (int kt=0; kt<19; ++kt){
    int row = tid>>1, half = (tid&1)*16;
    const unsigned short* sp = (kt<16) ? (hbf_in + row*512 + kt*32 + half)
                                       : (ubf + row*96 + (kt-16)*32 + half);
    *(float4*)&at[row*40 + half]     = *(const float4*)sp;
    *(float4*)&at[row*40 + half + 8] = *(const float4*)(sp + 8);
    __syncthreads();
    bf16x8 bfrag = (kt<16)
      ? *(const bf16x8*)(whh_bf + (size_t)ow*512 + kt*32 + lk)
      : *(const bf16x8*)(wih_bf + (size_t)ow*96 + (kt-16)*32 + lk);
    #pragma unroll
    for (int nt=0; nt<8; ++nt){
      bf16x8 afrag = *(const bf16x8*)&at[(nt*16 + lr)*40 + lk];
      acc[nt] = __builtin_amdgcn_mfma_f32_16x16x32_bf16(afrag, bfrag, acc[nt], 0,0,0);
    }
    __syncthreads();
  }
  float gb = gbias[ow];
  #pragma unroll
  for (int nt=0; nt<8; ++nt){
    #pragma unroll
    for (int i=0;i<4;i++){
      int nn = nt*16 + (l>>4)*4 + i;
      gsh[w][nn][lr] = acc[nt][i] + gb;
    }
  }
  __syncthreads();
  // cell update: 2048 cells (128 samples x 16 cols), 8 per thread
  #pragma unroll
  for (int c = tid*8; c < tid*8+8; ++c){
    int nn = c >> 4, j = c & 15;
    int hidx = b*16 + j;
    float gi = gsh[0][nn][j], gf = gsh[1][nn][j], gg = gsh[2][nn][j], go = gsh[3][nn][j];
    float cc = cbuf[nn*512 + hidx];
    float cs = fsigm(gf)*cc + fsigm(gi)*ftanh(gg);
    float h = fsigm(go)*ftanh(cs);
    cbuf[nn*512 + hidx] = cs;
    hbuf[nn*512 + hidx] = h;
    unsigned short hb = f2bf(h);
    hbf_out[nn*512 + hidx] = hb;
    cbf[(size_t)(nn*TT + t)*608 + hidx] = hb;
  }
}

// ---------------- comb-input xe/se slices ----------------
__global__ __launch_bounds__(256) void k_cbf_xs(const float* __restrict__ xe, const float* __restrict__ se,
                                                unsigned short* __restrict__ cbf){
  int idx = blockIdx.x*256 + threadIdx.x;
  if (idx >= TN*TT*32) return;
  int j = idx & 31, r = idx >> 5;
  int n = r >> 6;
  if (j < 16) cbf[(size_t)r*608 + 576 + j] = f2bf(xe[r*16 + j]);
  else        cbf[(size_t)r*608 + 592 + (j-16)] = f2bf(se[n*16 + (j-16)]);
}

// ---------------- comb GEMM: y = tanh(cin @ comb_w.T + comb_b), bf16 out ----------------
__global__ __launch_bounds__(256) void k_comb(const unsigned short* __restrict__ cbf,
    const unsigned short* __restrict__ cwbf, const float* __restrict__ comb_b,
    unsigned short* __restrict__ ybf){
  int mbase = blockIdx.x*128, obase = blockIdx.y*128;
  int tid = threadIdx.x, w = tid>>6, l = tid&63;
  int lr = l&15, lk = (l>>4)*8;
  __shared__ unsigned short at[128*40];
  f32x4 acc[8][2];
  #pragma unroll
  for (int m=0;m<8;m++){ acc[m][0] = (f32x4){0,0,0,0}; acc[m][1] = (f32x4){0,0,0,0}; }
  for (int kt=0; kt<19; ++kt){
    int row = tid>>1, half = (tid&1)*16;
    const unsigned short* sp = cbf + (size_t)(mbase+row)*608 + kt*32 + half;
    *(float4*)&at[row*40 + half]     = *(const float4*)sp;
    *(float4*)&at[row*40 + half + 8] = *(const float4*)(sp + 8);
    __syncthreads();
    bf16x8 b0 = *(const bf16x8*)(cwbf + (size_t)(obase + (2*w+0)*16 + lr)*608 + kt*32 + lk);
    bf16x8 b1 = *(const bf16x8*)(cwbf + (size_t)(obase + (2*w+1)*16 + lr)*608 + kt*32 + lk);
    #pragma unroll
    for (int m=0;m<8;m++){
      bf16x8 afrag = *(const bf16x8*)&at[(m*16+lr)*40 + lk];
      acc[m][0] = __builtin_amdgcn_mfma_f32_16x16x32_bf16(afrag, b0, acc[m][0], 0,0,0);
      acc[m][1] = __builtin_amdgcn_mfma_f32_16x16x32_bf16(afrag, b1, acc[m][1], 0,0,0);
    }
    __syncthreads();
  }
  #pragma unroll
  for (int m=0;m<8;m++){
    #pragma unroll
    for (int j=0;j<2;j++){
      int o = obase + (2*w+j)*16 + lr;
      float cb = comb_b[o];
      #pragma unroll
      for (int i=0;i<4;i++){
        int r = mbase + m*16 + (l>>4)*4 + i;
        ybf[(size_t)r*1024 + o] = f2bf(ftanh(acc[m][j][i] + cb));
      }
    }
  }
}

// ---------------- out GEMM: obuf = y @ out_w.T + out_b (N padded 121->128) ----------------
__global__ __launch_bounds__(256) void k_out(const unsigned short* __restrict__ ybf,
    const unsigned short* __restrict__ owbf, const float* __restrict__ obias,
    float* __restrict__ obuf){
  int mbase = blockIdx.x*128;
  int tid = threadIdx.x, w = tid>>6, l = tid&63;
  int lr = l&15, lk = (l>>4)*8;
  __shared__ unsigned short at[128*40];
  f32x4 acc[8][2];
  #pragma unroll
  for (int m=0;m<8;m++){ acc[m][0] = (f32x4){0,0,0,0}; acc[m][1] = (f32x4){0,0,0,0}; }
  for (int kt=0; kt<32; ++kt){
    int row = tid>>1, half = (tid&1)*16;
    const unsigned short* sp = ybf + (size_t)(mbase+row)*1024 + kt*32 + half;
    *(float4*)&at[row*40 + half]     = *(const float4*)sp;
    *(float4*)&at[row*40 + half + 8] = *(const float4*)(sp + 8);
    __syncthreads();
    bf16x8 b0 = *(const bf16x8*)(owbf + ((2*w+0)*16 + lr)*1024 + kt*32 + lk);
    bf16x8 b1 = *(const bf16x8*)(owbf + ((2*w+1)*16 + lr)*1024 + kt*32 + lk);
    #pragma unroll
    for (int m=0;m<8;m++){
      bf16x8 afrag = *(const bf16x8*)&at[(m*16+lr)*40 + lk];
      acc[m][0] = __builtin_amdgcn_mfma_f32_16x16x32_bf16(afrag, b0, acc[m][0], 0,0,0);
      acc[m][1] = __builtin_amdgcn_mfma_f32_16x16x32_bf16(afrag, b1, acc[m][1], 0,0,0);
    }
    __syncthreads();
  }
  #pragma unroll
  for (int m=0;m<8;m++){
    #pragma unroll
    for (int j=0;j<2;j++){
      int o = (2*w+j)*16 + lr;
      float ob = obias[o];
      #pragma unroll
      for (int i=0;i<4;i++){
        int r = mbase + m*16 + (l>>4)*4 + i;
        obuf[(size_t)r*128 + o] = acc[m][j][i] + ob;
      }
    }
  }
}

// ---------------- postprocess ----------------
__global__ __launch_bounds__(256) void k_post(const float* __restrict__ obuf, float* __restrict__ out){
  int r = blockIdx.x*256 + threadIdx.x;
  if (r >= TN*TT) return;
  const float* row = obuf + (size_t)r*128;
  float mx = -1e30f;
  #pragma unroll
  for (int k2=0;k2<20;k2++) mx = fmaxf(mx, row[k2]);
  float e[20]; float s = 0;
  #pragma unroll
  for (int k2=0;k2<20;k2++){ e[k2] = __expf(row[k2]-mx); s += e[k2]; }
  float inv = __builtin_amdgcn_rcpf(s);
  float* mixo  = out;
  float* meano = out + 163840;
  float* scaleo= out + 491520;
  float* corro = out + 819200;
  float* vlogo = out + 983040;
  #pragma unroll
  for (int k2=0;k2<20;k2++) mixo[r*20+k2] = e[k2]*inv;
  #pragma unroll
  for (int j=0;j<40;j++) meano[r*40+j] = row[20+j];
  #pragma unroll
  for (int j=0;j<40;j++) scaleo[r*40+j] = __expf(row[60+j]);
  #pragma unroll
  for (int k2=0;k2<20;k2++) corro[r*20+k2] = ftanh(row[100+k2]);
  vlogo[r] = row[120];
}

extern "C" void kernel_launch(void* const* d_in, const int* in_sizes, int n_in,
                              void* d_out, int out_size, void* d_ws, size_t ws_size,
                              hipStream_t stream){
  const float* x       = (const float*)d_in[0];
  const float* x_canv  = (const float*)d_in[1];
  const float* start_  = (const float*)d_in[2];
  const float* conv1_w = (const float*)d_in[3];
  const float* conv1_b = (const float*)d_in[4];
  const float* conv2_w = (const float*)d_in[5];
  const float* conv2_b = (const float*)d_in[6];
  const float* conv3_w = (const float*)d_in[7];
  const float* conv3_b = (const float*)d_in[8];
  const float* init_w  = (const float*)d_in[9];
  const float* init_b  = (const float*)d_in[10];
  const float* Uw      = (const float*)d_in[11];
  const float* Ub      = (const float*)d_in[12];
  const float* Ww      = (const float*)d_in[13];
  const float* Wb      = (const float*)d_in[14];
  const float* vw      = (const float*)d_in[15];
  const float* vb      = (const float*)d_in[16];
  const float* beta_w  = (const float*)d_in[17];
  const float* beta_b  = (const float*)d_in[18];
  const float* xemb_w  = (const float*)d_in[19];
  const float* xemb_b  = (const float*)d_in[20];
  const float* semb_w  = (const float*)d_in[21];
  const float* semb_b  = (const float*)d_in[22];
  const float* Wih     = (const float*)d_in[23];
  const float* Whh     = (const float*)d_in[24];
  const float* bih     = (const float*)d_in[25];
  const float* bhh     = (const float*)d_in[26];
  const float* comb_w  = (const float*)d_in[27];
  const float* comb_b  = (const float*)d_in[28];
  const float* out_w   = (const float*)d_in[29];
  const float* out_b   = (const float*)d_in[30];
  (void)in_sizes; (void)n_in; (void)out_size; (void)ws_size;

  char* wsb = (char*)d_ws;
  size_t off = 0;
  auto alloc = [&](size_t bytes)->char*{
    char* p = wsb + off;
    off = (off + bytes + 255) & ~(size_t)255;
    return p;
  };
  float*          c1     = (float*)alloc((size_t)TN*16*784*4);
  unsigned short* a2     = (unsigned short*)alloc((size_t)100352*160*2);  // a3 aliases a2
  unsigned short* a3     = a2;
  unsigned short* c2bf   = (unsigned short*)alloc((size_t)100352*32*2);
  float*          af     = (float*)alloc((size_t)TN*196*64*4);
  unsigned short* abf    = (unsigned short*)alloc((size_t)TN*196*64*2);
  float*          amean  = (float*)alloc((size_t)TN*64*4);
  float*          xe     = (float*)alloc((size_t)TN*TT*16*4);
  float*          se     = (float*)alloc((size_t)TN*16*4);
  float*          waT    = (float*)alloc((size_t)TN*128*196*4);
  float*          hbuf   = (float*)alloc((size_t)TN*512*4);
  float*          cbuf   = (float*)alloc((size_t)TN*512*4);
  unsigned short* hbfA   = (unsigned short*)alloc((size_t)TN*512*2);
  unsigned short* hbfB   = (unsigned short*)alloc((size_t)TN*512*2);
  unsigned short* ubf    = (unsigned short*)alloc((size_t)TN*96*2);
  unsigned short* cbf    = (unsigned short*)alloc((size_t)TN*TT*608*2);
  unsigned short* ybf    = (unsigned short*)alloc((size_t)TN*TT*1024*2);
  float*          obuf   = (float*)alloc((size_t)TN*TT*128*4);
  unsigned short* whh_bf = (unsigned short*)alloc((size_t)2048*512*2);
  unsigned short* wih_bf = (unsigned short*)alloc((size_t)2048*96*2);
  float*          gbias  = (float*)alloc((size_t)2048*4);
  unsigned short* cwbf   = (unsigned short*)alloc((size_t)1024*608*2);
  unsigned short* owbf   = (unsigned short*)alloc((size_t)128*1024*2);
  float*          obias  = (float*)alloc((size_t)128*4);
  float*          uwT    = (float*)alloc((size_t)512*128*4);
  float*          bwT    = (float*)alloc((size_t)512*64*4);
  unsigned short* wwbf   = (unsigned short*)alloc((size_t)128*64*2);
  unsigned short* w2b    = (unsigned short*)alloc((size_t)32*160*2);
  unsigned short* w3b    = (unsigned short*)alloc((size_t)64*320*2);

  hipLaunchKernelGGL(k_conv1, dim3(6272), dim3(256), 0, stream, x_canv, conv1_w, conv1_b, c1);
  hipLaunchKernelGGL(k_prep, dim3(8333), dim3(256), 0, stream,
                     Whh, Wih, bih, bhh, comb_w, out_w, out_b, Uw, beta_w, Ww, conv2_w, conv3_w,
                     whh_bf, wih_bf, gbias, cwbf, owbf, obias, uwT, bwT, wwbf, w2b, w3b);
  hipLaunchKernelGGL(k_im2col2, dim3(62720), dim3(256), 0, stream, c1, a2);
  hipLaunchKernelGGL(k_gconv2, dim3(784), dim3(256), 0, stream, a2, w2b, conv2_b, c2bf);
  hipLaunchKernelGGL(k_im2col3, dim3(31360), dim3(256), 0, stream, c2bf, a3);
  hipLaunchKernelGGL(k_gconv3, dim3(196), dim3(256), 0, stream, a3, w3b, conv3_b, af, abf);
  hipLaunchKernelGGL(k_amean, dim3(128), dim3(64), 0, stream, af, amean);
  hipLaunchKernelGGL(k_embed, dim3(520), dim3(256), 0, stream, x, start_, xemb_w, xemb_b, semb_w, semb_b, xe, se);
  hipLaunchKernelGGL(k_init, dim3(512), dim3(256), 0, stream, amean, se, init_w, init_b, hbuf, cbuf);
  hipLaunchKernelGGL(k_wa, dim3(196), dim3(256), 0, stream, abf, wwbf, Wb, waT);
  hipLaunchKernelGGL(k_cbf_xs, dim3(1024), dim3(256), 0, stream, xe, se, cbf);

  for (int t = 0; t < TT; ++t){
    unsigned short* hin  = (t & 1) ? hbfB : hbfA;
    unsigned short* hout = (t & 1) ? hbfA : hbfB;
    hipLaunchKernelGGL(k_stepA, dim3(128), dim3(256), 0, stream, t,
                       hbuf, uwT, Ub, bwT, beta_b, vw, vb, waT, af, xe,
                       hbfA, ubf, cbf);
    hipLaunchKernelGGL(k_stepB, dim3(32), dim3(256), 0, stream, t,
                       hin, ubf, whh_bf, wih_bf, gbias, cbuf, hbuf, hout, cbf);
  }

  hipLaunchKernelGGL(k_comb, dim3(64, 8), dim3(256), 0, stream, cbf, cwbf, comb_b, ybf);
  hipLaunchKernelGGL(k_out, dim3(64), dim3(256), 0, stream, ybf, owbf, obias, obuf);
  hipLaunchKernelGGL(k_post, dim3(32), dim3(256), 0, stream, obuf, (float*)d_out);
}